// Round 2
// baseline (265.454 us; speedup 1.0000x reference)
//
#include <hip/hip_runtime.h>
#include <hip/hip_bf16.h>

// HardAttention: out = tanh([context|output] @ W^T + b)  (GEMM M=16384,K=1024,N=512, bf16 MFMA)
//                attn = constant one-hot [4,4096,4096]   (256 MiB write-bound fill)
// Fused single kernel. Round-1 lesson: role-by-range serialized the phases
// (first ~512 co-resident blocks were all GEMM). Roles are now interleaved
// (bid&3): every residency wave holds a 1:3 GEMM:fill mix -> stores overlap MFMA.

typedef __attribute__((ext_vector_type(8))) short bf16x8;   // 8 bf16 = 4 VGPRs
typedef __attribute__((ext_vector_type(4))) float f32x4;

#define B_N 4
#define L_N 4096
#define S_N 4096
#define D_N 512
#define M_N (B_N * L_N)   // 16384
#define K_N (2 * D_N)     // 1024

#define BM 128
#define BN 128
#define GEMM_BLOCKS ((M_N / BM) * (D_N / BN))  // 128 * 4 = 512
#define FILL_BLOCKS 1536
#define TOTAL_BLOCKS (GEMM_BLOCKS + FILL_BLOCKS)
#define NTHREADS 256

static __device__ __forceinline__ short f2bf(float f) {
  unsigned u = __builtin_bit_cast(unsigned, f);
  u += 0x7fffu + ((u >> 16) & 1u);   // RNE
  return (short)(u >> 16);
}

static __device__ __forceinline__ bf16x8 pack8(f32x4 a, f32x4 b) {
  bf16x8 r;
  r[0] = f2bf(a.x); r[1] = f2bf(a.y); r[2] = f2bf(a.z); r[3] = f2bf(a.w);
  r[4] = f2bf(b.x); r[5] = f2bf(b.y); r[6] = f2bf(b.z); r[7] = f2bf(b.w);
  return r;
}

__global__ __launch_bounds__(NTHREADS, 2)
void hardattn_fused(const float* __restrict__ outp,   // [B,L,D] "output"
                    const float* __restrict__ ctx,    // [B,S,D] "context"
                    const float* __restrict__ W,      // [D, 2D] row-major = [N=512][K=1024]
                    const float* __restrict__ bias,   // [D]
                    float* __restrict__ dout)         // out [M,512] then attn [B,L,S]
{
  __shared__ char As[128 * 128];
  __shared__ char Bs[128 * 128];

  const int bid = blockIdx.x;
  const int tid = threadIdx.x;

  if ((bid & 3) != 0) {
    // ---------------- attn fill: 256 MiB one-hot (3 of every 4 blocks) ----------------
    const int fid = bid - (bid >> 2) - 1;            // contiguous [0, FILL_BLOCKS)
    float* attn = dout + (size_t)M_N * D_N;          // offset 8,388,608 floats
    const int total4 = (B_N * L_N * (S_N / 4));      // 16,777,216 float4s
    const int stride = FILL_BLOCKS * NTHREADS;
    for (int i = fid * NTHREADS + tid; i < total4; i += stride) {
      const int f = i << 2;                          // flat float index < 2^26
      const int col = f & (S_N - 1);
      const int l   = (f >> 12) & (L_N - 1);
      f32x4 v;
      v.x = (col     == l) ? 1.0f : 0.0f;
      v.y = (col + 1 == l) ? 1.0f : 0.0f;
      v.z = (col + 2 == l) ? 1.0f : 0.0f;
      v.w = (col + 3 == l) ? 1.0f : 0.0f;
      __builtin_nontemporal_store(v, (f32x4*)attn + i);  // don't pollute L2/L3
    }
    return;
  }

  // ---------------- GEMM: out = tanh(A @ W^T + b) (1 of every 4 blocks) ----------------
  // A[m,k] = (k<512) ? ctx[m*512+k] : outp[m*512+k-512]   (m = b*4096+l)
  const int gid = bid >> 2;           // [0, GEMM_BLOCKS)
  const int mt = gid >> 2;            // 4 consecutive gemm ids share the A panel
  const int nt = gid & 3;
  const int row0 = mt * BM;
  const int col0 = nt * BN;
  const int lane = tid & 63;
  const int wid  = tid >> 6;
  const int wr = (wid >> 1) * 64;     // wave 64x64 sub-tile
  const int wc = (wid & 1) * 64;

  f32x4 acc[4][4] = {};

  // staging: thread -> row sr (0..127), half sh (cols [sh,sh+32) of the 64-col tile)
  const int sr = tid >> 1;
  const int sh = (tid & 1) * 32;
  const float* bRowW = W + (size_t)(col0 + sr) * K_N;

  for (int kt = 0; kt < 16; ++kt) {
    const float* ap = ((kt < 8) ? ctx : outp) + (size_t)(row0 + sr) * D_N + ((kt & 7) * 64 + sh);
    const float* bp = bRowW + (kt * 64 + sh);
    f32x4 a4[8], b4[8];
#pragma unroll
    for (int q = 0; q < 8; ++q) a4[q] = ((const f32x4*)ap)[q];
#pragma unroll
    for (int q = 0; q < 8; ++q) b4[q] = ((const f32x4*)bp)[q];
    bf16x8 pa[4], pb[4];
#pragma unroll
    for (int q = 0; q < 4; ++q) {
      pa[q] = pack8(a4[2 * q], a4[2 * q + 1]);
      pb[q] = pack8(b4[2 * q], b4[2 * q + 1]);
    }
    __syncthreads();   // previous tile's reads done
    {
      const int wbase = sr * 128;
      const int wswz  = (sr & 7) << 4;
#pragma unroll
      for (int q = 0; q < 4; ++q) {
        const int kb = sh * 2 + q * 16;          // byte offset within 128B row
        *(bf16x8*)&As[wbase + (kb ^ wswz)] = pa[q];
        *(bf16x8*)&Bs[wbase + (kb ^ wswz)] = pb[q];
      }
    }
    __syncthreads();   // tile ready

#pragma unroll
    for (int kk = 0; kk < 2; ++kk) {
      const int kb = kk * 64 + ((lane >> 4) << 4);
      bf16x8 af[4], bfr[4];
#pragma unroll
      for (int i = 0; i < 4; ++i) {
        const int ar = wr + i * 16 + (lane & 15);
        af[i]  = *(const bf16x8*)&As[ar * 128 + (kb ^ ((ar & 7) << 4))];
        const int br = wc + i * 16 + (lane & 15);
        bfr[i] = *(const bf16x8*)&Bs[br * 128 + (kb ^ ((br & 7) << 4))];
      }
#pragma unroll
      for (int i = 0; i < 4; ++i)
#pragma unroll
        for (int j = 0; j < 4; ++j)
          acc[i][j] = __builtin_amdgcn_mfma_f32_16x16x32_bf16(af[i], bfr[j], acc[i][j], 0, 0, 0);
    }
  }

  // epilogue: C/D layout col=lane&15, row=(lane>>4)*4+reg  (verified m89/m91)
  const int r0  = row0 + wr + ((lane >> 4) << 2);
  const int c0g = col0 + wc + (lane & 15);
  float bv[4];
#pragma unroll
  for (int j = 0; j < 4; ++j) bv[j] = bias[c0g + j * 16];
#pragma unroll
  for (int i = 0; i < 4; ++i)
#pragma unroll
    for (int j = 0; j < 4; ++j)
#pragma unroll
      for (int r = 0; r < 4; ++r) {
        const int m = r0 + i * 16 + r;
        const int n = c0g + j * 16;
        dout[(size_t)m * D_N + n] = tanhf(acc[i][j][r] + bv[j]);
      }
}

extern "C" void kernel_launch(void* const* d_in, const int* in_sizes, int n_in,
                              void* d_out, int out_size, void* d_ws, size_t ws_size,
                              hipStream_t stream) {
  const float* outp = (const float*)d_in[0];
  const float* ctx  = (const float*)d_in[1];
  const float* W    = (const float*)d_in[2];
  const float* bias = (const float*)d_in[3];
  float* dout = (float*)d_out;
  hipLaunchKernelGGL(hardattn_fused, dim3(TOTAL_BLOCKS), dim3(NTHREADS),
                     0, stream, outp, ctx, W, bias, dout);
}

// Round 3
// 107.652 us; speedup vs baseline: 2.4659x; 2.4659x over previous
//
#include <hip/hip_runtime.h>
#include <hip/hip_bf16.h>

// HardAttention = GEMM out=tanh([ctx|outp]@W^T+b) (M=16384,K=1024,N=512) + 256MiB one-hot fill.
// Round-2 lesson: mixing the store-firehose with a barriered GEMM collapses to latency-bound
// (15% BW, MfmaUtil 2%). Round 3: three serialized kernels, each at its own roofline:
//   K1: f32->bf16 convert of A and W, written PRE-SWIZZLED as LDS tile images into the
//       attn region of d_out (linear global_load_lds dest + inverse-swz source + swz read).
//   K2: m97-template GEMM: global_load_lds dwordx4 staging, swizzled ds_read_b128, MFMA.
//   K3: one-hot fill overwrites the whole attn region (including the temp images).

typedef __attribute__((ext_vector_type(8))) short bf16x8;   // 8 bf16 = 4 VGPRs
typedef __attribute__((ext_vector_type(4))) float f32x4;

#define B_N 4
#define L_N 4096
#define S_N 4096
#define D_N 512
#define M_N (B_N * L_N)   // 16384
#define K_N (2 * D_N)     // 1024

#define BM 128
#define BN 128
#define GEMM_BLOCKS ((M_N / BM) * (D_N / BN))  // 512
#define NTHREADS 256

#define AIMG_CHUNKS (128 * 16 * 128 * 8)      // 2,097,152 16B chunks = 32 MiB
#define WIMG_CHUNKS (4 * 16 * 128 * 8)        // 65,536    16B chunks = 1 MiB

static __device__ __forceinline__ short f2bf(float f) {
  unsigned u = __builtin_bit_cast(unsigned, f);
  u += 0x7fffu + ((u >> 16) & 1u);   // RNE
  return (short)(u >> 16);
}

static __device__ __forceinline__ bf16x8 pack8(f32x4 a, f32x4 b) {
  bf16x8 r;
  r[0] = f2bf(a.x); r[1] = f2bf(a.y); r[2] = f2bf(a.z); r[3] = f2bf(a.w);
  r[4] = f2bf(b.x); r[5] = f2bf(b.y); r[6] = f2bf(b.z); r[7] = f2bf(b.w);
  return r;
}

static __device__ __forceinline__ void gload_lds16(const void* g, void* l) {
  __builtin_amdgcn_global_load_lds(
      (const __attribute__((address_space(1))) unsigned*)g,
      (__attribute__((address_space(3))) unsigned*)l, 16, 0, 0);
}

// ---------------- K1: build bf16 pre-swizzled tile images ----------------
// Image chunk layout: img[(tile*128 + row)*8 + c] (16B) holds 8 bf16 of
// SRC[row][ (c ^ (row&7))*8 .. +8 ) of that 128x64 K-tile, so a LINEAR copy
// into LDS yields LDS[row*128 + (kb ^ ((row&7)<<4))] == SRCbytes[row][kb].
__global__ __launch_bounds__(NTHREADS)
void prep_images(const float* __restrict__ outp, const float* __restrict__ ctx,
                 const float* __restrict__ W, float* __restrict__ dout)
{
  char* attnB = (char*)(dout + (size_t)M_N * D_N);
  char* Aimg = attnB;                         // 32 MiB
  char* Wimg = attnB + (32u << 20);           // 1 MiB
  const int stride = gridDim.x * blockDim.x;
  for (int h = blockIdx.x * blockDim.x + threadIdx.x;
       h < AIMG_CHUNKS + WIMG_CHUNKS; h += stride) {
    if (h < AIMG_CHUNKS) {
      const int c   = h & 7;
      const int row = (h >> 3) & 127;
      const int kt  = (h >> 10) & 15;
      const int mt  = h >> 14;
      const int g   = c ^ (row & 7);
      const float* src = ((kt < 8) ? ctx : outp)
                       + (size_t)(mt * 128 + row) * D_N + ((kt & 7) * 64 + g * 8);
      f32x4 a = ((const f32x4*)src)[0], b = ((const f32x4*)src)[1];
      *(bf16x8*)(Aimg + (size_t)h * 16) = pack8(a, b);
    } else {
      const int h2  = h - AIMG_CHUNKS;
      const int c   = h2 & 7;
      const int row = (h2 >> 3) & 127;
      const int kt  = (h2 >> 10) & 15;
      const int nt  = h2 >> 14;
      const int g   = c ^ (row & 7);
      const float* src = W + (size_t)(nt * 128 + row) * K_N + (kt * 64 + g * 8);
      f32x4 a = ((const f32x4*)src)[0], b = ((const f32x4*)src)[1];
      *(bf16x8*)(Wimg + (size_t)h2 * 16) = pack8(a, b);
    }
  }
}

// ---------------- K2: bf16 MFMA GEMM (m97 structure) ----------------
__global__ __launch_bounds__(NTHREADS, 2)
void gemm_tanh(const float* __restrict__ bias, float* dout)
{
  __shared__ char As[16384];
  __shared__ char Bs[16384];

  const char* attnB = (const char*)(dout + (size_t)M_N * D_N);
  const char* Aimg = attnB;
  const char* Wimg = attnB + (32u << 20);

  const int bid = blockIdx.x;
  const int tid = threadIdx.x;
  const int lane = tid & 63;
  const int wid  = tid >> 6;
  const int mt = bid >> 2;
  const int nt = bid & 3;
  const int row0 = mt * BM;
  const int col0 = nt * BN;
  const int wr = (wid >> 1) * 64;
  const int wc = (wid & 1) * 64;

  f32x4 acc[4][4] = {};

  const int soff = wid * 1024 + lane * 16;   // per-lane src offset; LDS base = wid*1024

  for (int kt = 0; kt < 16; ++kt) {
    const char* ab = Aimg + (size_t)(mt * 16 + kt) * 16384;
    const char* bb = Wimg + (size_t)(nt * 16 + kt) * 16384;
#pragma unroll
    for (int q = 0; q < 4; ++q) {
      gload_lds16(ab + soff + q * 4096, As + wid * 1024 + q * 4096);
      gload_lds16(bb + soff + q * 4096, Bs + wid * 1024 + q * 4096);
    }
    __syncthreads();   // vmcnt(0) drain: tile ready

#pragma unroll
    for (int kk = 0; kk < 2; ++kk) {
      const int kb = kk * 64 + ((lane >> 4) << 4);
      bf16x8 af[4], bfr[4];
#pragma unroll
      for (int i = 0; i < 4; ++i) {
        const int ar = wr + i * 16 + (lane & 15);
        af[i]  = *(const bf16x8*)&As[ar * 128 + (kb ^ ((ar & 7) << 4))];
        const int br = wc + i * 16 + (lane & 15);
        bfr[i] = *(const bf16x8*)&Bs[br * 128 + (kb ^ ((br & 7) << 4))];
      }
#pragma unroll
      for (int i = 0; i < 4; ++i)
#pragma unroll
        for (int j = 0; j < 4; ++j)
          acc[i][j] = __builtin_amdgcn_mfma_f32_16x16x32_bf16(af[i], bfr[j], acc[i][j], 0, 0, 0);
    }
    __syncthreads();   // reads done before next tile overwrites
  }

  // epilogue: C/D layout col=lane&15, row=(lane>>4)*4+reg (verified m89/m91)
  const int r0  = row0 + wr + ((lane >> 4) << 2);
  const int c0g = col0 + wc + (lane & 15);
  float bv[4];
#pragma unroll
  for (int j = 0; j < 4; ++j) bv[j] = bias[c0g + j * 16];
#pragma unroll
  for (int i = 0; i < 4; ++i)
#pragma unroll
    for (int j = 0; j < 4; ++j)
#pragma unroll
      for (int r = 0; r < 4; ++r) {
        const int m = r0 + i * 16 + r;
        const int n = c0g + j * 16;
        dout[(size_t)m * D_N + n] = tanhf(acc[i][j][r] + bv[j]);
      }
}

// ---------------- K3: one-hot attn fill (overwrites images too) ----------------
__global__ __launch_bounds__(NTHREADS)
void fill_attn(float* __restrict__ dout)
{
  float* attn = dout + (size_t)M_N * D_N;
  const int total4 = (B_N * L_N * (S_N / 4));      // 16,777,216 float4s
  const int stride = gridDim.x * blockDim.x;
  for (int i = blockIdx.x * blockDim.x + threadIdx.x; i < total4; i += stride) {
    const int f = i << 2;
    const int col = f & (S_N - 1);
    const int l   = (f >> 12) & (L_N - 1);
    f32x4 v;
    v.x = (col     == l) ? 1.0f : 0.0f;
    v.y = (col + 1 == l) ? 1.0f : 0.0f;
    v.z = (col + 2 == l) ? 1.0f : 0.0f;
    v.w = (col + 3 == l) ? 1.0f : 0.0f;
    __builtin_nontemporal_store(v, (f32x4*)attn + i);
  }
}

extern "C" void kernel_launch(void* const* d_in, const int* in_sizes, int n_in,
                              void* d_out, int out_size, void* d_ws, size_t ws_size,
                              hipStream_t stream) {
  const float* outp = (const float*)d_in[0];
  const float* ctx  = (const float*)d_in[1];
  const float* W    = (const float*)d_in[2];
  const float* bias = (const float*)d_in[3];
  float* dout = (float*)d_out;
  hipLaunchKernelGGL(prep_images, dim3(2048), dim3(NTHREADS), 0, stream, outp, ctx, W, dout);
  hipLaunchKernelGGL(gemm_tanh,  dim3(GEMM_BLOCKS), dim3(NTHREADS), 0, stream, bias, dout);
  hipLaunchKernelGGL(fill_attn,  dim3(2048), dim3(NTHREADS), 0, stream, dout);
}